// Round 9
// baseline (197.012 us; speedup 1.0000x reference)
//
#include <hip/hip_runtime.h>
#include <hip/hip_bf16.h>

// Problem dims: B=16, N=1024, E=d_head=128, H=8; M = 16384 rows
typedef __bf16 bf16x8 __attribute__((ext_vector_type(8)));
typedef _Float16 f16x8 __attribute__((ext_vector_type(8)));
typedef float f32x4 __attribute__((ext_vector_type(4)));

__device__ __forceinline__ unsigned short f2bf(float f) {
  union { __hip_bfloat16 h; unsigned short u; } cv;
  cv.h = __float2bfloat16(f);
  return cv.u;
}
__device__ __forceinline__ unsigned short f2h(float f) {
  union { _Float16 h; unsigned short u; } cv;
  cv.h = (_Float16)f;
  return cv.u;
}
// pack 2 f32 -> 2 f16 in one dword (v_cvt_pkrtz_f16_f32); a -> bits[15:0]
__device__ __forceinline__ unsigned int pkrtz(float a, float b) {
  auto h = __builtin_amdgcn_cvt_pkrtz(a, b);  // __fp16 ext_vector(2)
  unsigned int u;
  __builtin_memcpy(&u, &h, 4);
  return u;
}

__device__ __forceinline__ bf16x8 ld_frag(const unsigned short* p) {
  bf16x8 v;
  __builtin_memcpy(&v, __builtin_assume_aligned(p, 16), 16);
  return v;
}
__device__ __forceinline__ f16x8 ld_f16x8(const unsigned short* p) {
  f16x8 v;
  __builtin_memcpy(&v, __builtin_assume_aligned(p, 16), 16);
  return v;
}
__device__ __forceinline__ uint4 ld16(const unsigned short* p) {
  uint4 v;
  __builtin_memcpy(&v, __builtin_assume_aligned(p, 16), 16);
  return v;
}
__device__ __forceinline__ void st16(unsigned short* p, uint4 v) {
  __builtin_memcpy(__builtin_assume_aligned(p, 16), &v, 16);
}
// async global->LDS DMA, 16 B per lane; lds dest is wave-uniform base + lane*16
__device__ __forceinline__ void dma16(const unsigned short* g, unsigned short* l) {
  __builtin_amdgcn_global_load_lds((const __attribute__((address_space(1))) void*)g,
                                   (__attribute__((address_space(3))) void*)l, 16, 0, 0);
}

// ---------------- LayerNorm + cast to bf16 -----------------
__global__ __launch_bounds__(256) void ln_kernel(const float* __restrict__ x,
                                                 const float* __restrict__ w,
                                                 const float* __restrict__ b,
                                                 unsigned short* __restrict__ xn) {
  int wave = threadIdx.x >> 6;
  int lane = threadIdx.x & 63;
  int row = blockIdx.x * 4 + wave;
  const float* xr = x + (size_t)row * 128;
  float2 v = *reinterpret_cast<const float2*>(xr + lane * 2);
  float s1 = v.x + v.y;
  float s2 = v.x * v.x + v.y * v.y;
#pragma unroll
  for (int off = 32; off > 0; off >>= 1) {
    s1 += __shfl_xor(s1, off, 64);
    s2 += __shfl_xor(s2, off, 64);
  }
  float mu = s1 * (1.0f / 128.0f);
  float var = s2 * (1.0f / 128.0f) - mu * mu;
  float rstd = rsqrtf(var + 1e-5f);
  float a0 = (v.x - mu) * rstd * w[lane * 2] + b[lane * 2];
  float a1 = (v.y - mu) * rstd * w[lane * 2 + 1] + b[lane * 2 + 1];
  unsigned int pk = (unsigned int)f2bf(a0) | ((unsigned int)f2bf(a1) << 16);
  *reinterpret_cast<unsigned int*>(xn + (size_t)row * 128 + lane * 2) = pk;
}

// ---------------- transpose + cast fp32[R][C] -> bf16[C][R] -----------------
__global__ __launch_bounds__(256) void tcast_kernel(const float* __restrict__ in,
                                                    unsigned short* __restrict__ out,
                                                    int R, int C) {
  __shared__ float tile[32][33];
  int tx = threadIdx.x & 31, ty = threadIdx.x >> 5;
  int c0 = blockIdx.x * 32, r0 = blockIdx.y * 32;
#pragma unroll
  for (int k = 0; k < 4; k++)
    tile[ty + 8 * k][tx] = in[(size_t)(r0 + ty + 8 * k) * C + c0 + tx];
  __syncthreads();
#pragma unroll
  for (int k = 0; k < 4; k++)
    out[(size_t)(c0 + ty + 8 * k) * R + r0 + tx] = f2bf(tile[tx][ty + 8 * k]);
}

// ---------------- QKV GEMM, 128x128 tile, BK=64 x2 ----------------
// Q cols (0..1023, pre-scaled by scale[h]*log2e for exp2 softmax) and K cols
// -> qk bf16; V cols -> Vt[bh][d][n'] fp16, where n' is the PV-slot token
// permutation: t = 32c+16s+4q+r -> n' = 32c+8q+4s+r. This makes each attn
// lane's 8 P-values (tokens {16s+4*quad+r} from the QK^T C-layout) CONTIGUOUS
// in Vt, so the K=32 PV needs no cross-lane P redistribution (MFMA is
// k-order-invariant when A and B share the ordering).
__global__ __launch_bounds__(256) void qkv_gemm(const unsigned short* __restrict__ A,
                                                const unsigned short* __restrict__ Bt,
                                                const float* __restrict__ scale,
                                                unsigned short* __restrict__ qk,
                                                unsigned short* __restrict__ Vt) {
  __shared__ unsigned short Al[128 * 72];
  __shared__ unsigned short Bl[128 * 72];
  int t = threadIdx.x;
  int i0 = blockIdx.x * 128, c0 = blockIdx.y * 128;
  int lg = t & 7, rr = t >> 3;  // granule 0..7, row 0..31
  int w = t >> 6, lane = t & 63, l15 = lane & 15, quad = lane >> 4;
  int wy = (w >> 1) * 64, wx = (w & 1) * 64;
  const f32x4 fz = {0.f, 0.f, 0.f, 0.f};
  f32x4 acc[4][4];
#pragma unroll
  for (int i = 0; i < 4; i++)
#pragma unroll
    for (int j = 0; j < 4; j++) acc[i][j] = fz;

#pragma unroll
  for (int kt = 0; kt < 2; kt++) {
    int k0 = kt * 64;
    uint4 areg[4], breg[4];
#pragma unroll
    for (int p = 0; p < 4; p++)
      areg[p] = ld16(&A[(size_t)(i0 + rr + 32 * p) * 128 + k0 + lg * 8]);
#pragma unroll
    for (int p = 0; p < 4; p++)
      breg[p] = ld16(&Bt[(size_t)(c0 + rr + 32 * p) * 128 + k0 + lg * 8]);
    __syncthreads();
#pragma unroll
    for (int p = 0; p < 4; p++) st16(&Al[(rr + 32 * p) * 72 + lg * 8], areg[p]);
#pragma unroll
    for (int p = 0; p < 4; p++) st16(&Bl[(rr + 32 * p) * 72 + lg * 8], breg[p]);
    __syncthreads();
#pragma unroll
    for (int ks = 0; ks < 2; ks++) {
      bf16x8 af[4], bfr[4];
#pragma unroll
      for (int i = 0; i < 4; i++)
        af[i] = ld_frag(&Al[(wy + 16 * i + l15) * 72 + 32 * ks + quad * 8]);
#pragma unroll
      for (int j = 0; j < 4; j++)
        bfr[j] = ld_frag(&Bl[(wx + 16 * j + l15) * 72 + 32 * ks + quad * 8]);
#pragma unroll
      for (int i = 0; i < 4; i++)
#pragma unroll
        for (int j = 0; j < 4; j++)
          acc[i][j] = __builtin_amdgcn_mfma_f32_16x16x32_bf16(af[i], bfr[j], acc[i][j], 0, 0, 0);
    }
  }
  if (blockIdx.y < 16) {
    // Q blocks (y<8): scale[h]*log2e folded in (attn uses exp2f = v_exp_f32)
    float qsc = (blockIdx.y < 8) ? scale[blockIdx.y] * 1.44269504088896f : 1.0f;
#pragma unroll
    for (int i = 0; i < 4; i++)
#pragma unroll
      for (int j = 0; j < 4; j++)
#pragma unroll
        for (int r = 0; r < 4; r++) {
          int row = i0 + wy + 16 * i + quad * 4 + r;
          int col = c0 + wx + 16 * j + l15;
          qk[(size_t)row * 2048 + col] = f2bf(acc[i][j][r] * qsc);
        }
  } else {
    int vc0 = (blockIdx.y - 16) * 128;
#pragma unroll
    for (int i = 0; i < 4; i++)
#pragma unroll
      for (int j = 0; j < 4; j++) {
        int vcol = vc0 + wx + 16 * j + l15;   // 0..1023
        int hh = vcol >> 7, dd = vcol & 127;
        int row0 = i0 + wy + 16 * i + quad * 4;
        int bb = row0 >> 10, nn = row0 & 1023;
        // PV-slot permutation within each 32-token block (nn%4==0 -> the
        // ushort4 stays contiguous: only bits [4:2] of nn are remapped)
        int nnp = (nn & ~31) | (((nn >> 2) & 3) << 3) | (((nn >> 4) & 1) << 2) | (nn & 3);
        ushort4 pk;
        pk.x = f2h(acc[i][j][0]); pk.y = f2h(acc[i][j][1]);
        pk.z = f2h(acc[i][j][2]); pk.w = f2h(acc[i][j][3]);
        *reinterpret_cast<ushort4*>(Vt + (size_t)(bb * 8 + hh) * 131072 +
                                    (size_t)dd * 1024 + nnp) = pk;
      }
  }
}

// ---------------- Flash attention: 1 barrier/kt, K=32 PV, MFMA row-sum -----
// block = (b,h, 128-row Q tile); 4 waves x 32 rows (2 groups of 16).
// Structure (R8-proven): K+V double-buffered, 64 KB LDS, ONE __syncthreads
// per kt (drains DMAs issued a full iteration ago), prefetch K/V[kt+1] after
// it. PV at full-rate K=32 f16 with zero-shuffle P (Vt token-permuted).
// New vs R8 (VALU cuts, both compiler-managed):
//  - softmax uses __builtin_exp2f (native v_exp_f32; log2e pre-folded in Q):
//    deletes 32 v_mul/lane-kt. NO inline asm (R7's trans-op hazard lesson).
//  - denominator via ones-column MFMA: osum[g] += P x ones computes the
//    row-sum on the matrix pipe in C-layout (row=quad*4+r) — deletes 32
//    v_add/lane-kt AND the epilogue shuffle redistribution. Denominator sums
//    the same f16 P the numerator uses (consistent reweighting).
__global__ __launch_bounds__(256, 2) void attn_kernel(const unsigned short* __restrict__ qk,
                                                      const unsigned short* __restrict__ Vt,
                                                      unsigned short* __restrict__ aout) {
  __shared__ __align__(16) unsigned short Kl[2][64 * 128];  // 32 KB [kcol][d], granule-swizzled
  __shared__ __align__(16) unsigned short Vl[2][128 * 64];  // 32 KB [d][tok'], granule-swizzled
  int t = threadIdx.x;
  int idx = blockIdx.x;
  // same-bh q-tiles at blockIdx stride 128 (=0 mod 8) -> same XCD slot
  int bh = idx & 127, qt = idx >> 7;
  int b = bh >> 3, h = bh & 7;
  int q0 = qt * 128;
  int w = t >> 6, lane = t & 63, l15 = lane & 15, quad = lane >> 4;

  // Q fragments (B-operand layout: n=l15=qrow, k=quad*8+j), 2 groups of 16
  bf16x8 qf[2][4];
  {
    const unsigned short* qb = qk + (size_t)(b * 1024) * 2048 + h * 128;
#pragma unroll
    for (int g = 0; g < 2; g++) {
      const unsigned short* qp = qb + (size_t)(q0 + 32 * w + 16 * g + l15) * 2048;
#pragma unroll
      for (int ks = 0; ks < 4; ks++) qf[g][ks] = ld_frag(qp + 32 * ks + quad * 8);
    }
  }
  const f32x4 fz = {0.f, 0.f, 0.f, 0.f};
  f32x4 o[2][8];
#pragma unroll
  for (int g = 0; g < 2; g++)
#pragma unroll
    for (int i = 0; i < 8; i++) o[g][i] = fz;
  f32x4 osum[2] = {fz, fz};  // row-sum accumulator (C-layout: row=quad*4+r)
  const f16x8 vones = {1.f16, 1.f16, 1.f16, 1.f16, 1.f16, 1.f16, 1.f16, 1.f16};

  const unsigned short* kbase = qk + (size_t)(b * 1024) * 2048 + 1024 + h * 128;
  const unsigned short* vbase = Vt + (size_t)bh * 131072;

  // DMA lane mappings (4 K-chunks + 4 V-chunks per wave, 1 KB each)
  int koff[4], voff[4];
#pragma unroll
  for (int i = 0; i < 4; i++) {
    int c = w * 4 + i;
    int krow = c * 4 + (lane >> 4);                    // 0..63 (kcol)
    int kg = ((lane & 15) ^ (krow & 7)) * 8;           // 16B granule * 8 shorts
    koff[i] = krow * 2048 + kg;
    int vrow = c * 8 + (lane >> 3);                    // 0..127 (d)
    int vg = ((lane & 7) ^ ((vrow >> 1) & 7)) * 8;
    voff[i] = vrow * 1024 + vg;
  }

  // prologue: preload K[0] and V[0] into buffer 0
#pragma unroll
  for (int i = 0; i < 4; i++) {
    dma16(kbase + koff[i], &Kl[0][(w * 4 + i) * 512]);
    dma16(vbase + voff[i], &Vl[0][(w * 4 + i) * 512]);
  }

  for (int kt = 0; kt < 16; kt++) {
    int k0 = kt * 64;
    __syncthreads();  // drains K[kt]+V[kt] (issued a full iteration ago);
                      // all waves done reading buf[(kt+1)&1] one iter ago
    if (kt < 15) {
      int kn0 = (kt + 1) * 64;
      int nb = (kt + 1) & 1;
#pragma unroll
      for (int i = 0; i < 4; i++) {
        dma16(kbase + (size_t)kn0 * 2048 + koff[i], &Kl[nb][(w * 4 + i) * 512]);
        dma16(vbase + voff[i] + kn0, &Vl[nb][(w * 4 + i) * 512]);
      }
    }
    const unsigned short* Kc = Kl[kt & 1];
    const unsigned short* Vc = Vl[kt & 1];

    // ---- QK^T + exp2 + pack to K=32 A-frags (own lane's tokens only) ----
    f16x8 pa[2][2];  // [g][cp]; slots j=4s+r -> token 32cp+16s+4*quad+r
#pragma unroll
    for (int cp = 0; cp < 2; cp++) {
      unsigned int dw[2][4];
#pragma unroll
      for (int sub = 0; sub < 2; sub++) {
        int ct = cp * 2 + sub;
        f32x4 acc[2] = {fz, fz};
#pragma unroll
        for (int ks = 0; ks < 4; ks++) {
          bf16x8 kf = ld_frag(&Kc[(16 * ct + l15) * 128 + ((4 * ks + quad) ^ (l15 & 7)) * 8]);
#pragma unroll
          for (int g = 0; g < 2; g++)
            acc[g] = __builtin_amdgcn_mfma_f32_16x16x32_bf16(kf, qf[g][ks], acc[g], 0, 0, 0);
        }
#pragma unroll
        for (int g = 0; g < 2; g++) {
          float p[4];
          if ((q0 + 32 * w + 16 * g) == (k0 + 16 * ct)) {
#pragma unroll
            for (int r = 0; r < 4; r++)
              p[r] = ((quad * 4 + r) == l15) ? 0.f : __builtin_exp2f(acc[g][r]);
          } else {
#pragma unroll
            for (int r = 0; r < 4; r++) p[r] = __builtin_exp2f(acc[g][r]);
          }
          dw[g][sub * 2 + 0] = pkrtz(p[0], p[1]);
          dw[g][sub * 2 + 1] = pkrtz(p[2], p[3]);
        }
      }
#pragma unroll
      for (int g = 0; g < 2; g++) __builtin_memcpy(&pa[g][cp], dw[g], 16);
    }

    // ---- O += P * V at K=32; row-sum += P * ones (denominator on MFMA) ----
    // (V[kt] was drained by THIS iteration's top barrier; no mid barrier)
#pragma unroll
    for (int cp = 0; cp < 2; cp++) {
#pragma unroll
      for (int g = 0; g < 2; g++)
        osum[g] = __builtin_amdgcn_mfma_f32_16x16x32_f16(pa[g][cp], vones, osum[g], 0, 0, 0);
#pragma unroll
      for (int c8 = 0; c8 < 8; c8++) {
        // row d=16c8+l15; 16B granule (4cp+quad) swizzled by (d>>1)&7=(l15>>1)&7
        f16x8 vf = ld_f16x8(&Vc[(16 * c8 + l15) * 64 + ((4 * cp + quad) ^ ((l15 >> 1) & 7)) * 8]);
#pragma unroll
        for (int g = 0; g < 2; g++)
          o[g][c8] = __builtin_amdgcn_mfma_f32_16x16x32_f16(pa[g][cp], vf, o[g][c8], 0, 0, 0);
      }
    }
  }

  // epilogue: osum[g][r] = softmax denominator for qrow=quad*4+r (16g group),
  // already in the same C-layout as o — direct divide, no shuffles.
#pragma unroll
  for (int g = 0; g < 2; g++) {
#pragma unroll
    for (int r = 0; r < 4; r++) {
      float rl = 1.0f / osum[g][r];
      int row = b * 1024 + q0 + 32 * w + 16 * g + quad * 4 + r;
#pragma unroll
      for (int c8 = 0; c8 < 8; c8++) {
        int col = h * 128 + 16 * c8 + l15;
        aout[(size_t)row * 1024 + col] = f2bf(o[g][c8][r] * rl);
      }
    }
  }
}

// ---------------- output projection: out = aout @ w_proj + b_proj (fp32) ----
// 64-row x 64-col blocks (512 total -> 2/CU), BK=128 x 8
__global__ __launch_bounds__(256) void proj_gemm(const unsigned short* __restrict__ A,
                                                 const unsigned short* __restrict__ Bt,
                                                 const float* __restrict__ bias,
                                                 float* __restrict__ out) {
  __shared__ unsigned short Al[64 * 136];
  __shared__ unsigned short Bl[64 * 136];
  int t = threadIdx.x;
  int i0 = blockIdx.x * 64, c0 = blockIdx.y * 64;
  int w = t >> 6, lane = t & 63, l15 = lane & 15, quad = lane >> 4;
  int wy = (w >> 1) * 32, wx = (w & 1) * 32;
  const f32x4 fz = {0.f, 0.f, 0.f, 0.f};
  f32x4 acc[2][2];
#pragma unroll
  for (int i = 0; i < 2; i++)
#pragma unroll
    for (int j = 0; j < 2; j++) acc[i][j] = fz;
  int l = t & 15, rr = t >> 4;
  for (int kb = 0; kb < 8; kb++) {
    int k0 = kb * 128;
    uint4 areg[4], breg[4];
#pragma unroll
    for (int p = 0; p < 4; p++)
      areg[p] = ld16(&A[(size_t)(i0 + rr + 16 * p) * 1024 + k0 + l * 8]);
#pragma unroll
    for (int p = 0; p < 4; p++)
      breg[p] = ld16(&Bt[(size_t)(c0 + rr + 16 * p) * 1024 + k0 + l * 8]);
    __syncthreads();
#pragma unroll
    for (int p = 0; p < 4; p++) st16(&Al[(rr + 16 * p) * 136 + l * 8], areg[p]);
#pragma unroll
    for (int p = 0; p < 4; p++) st16(&Bl[(rr + 16 * p) * 136 + l * 8], breg[p]);
    __syncthreads();
#pragma unroll
    for (int ks = 0; ks < 4; ks++) {
      bf16x8 af[2], bfr[2];
#pragma unroll
      for (int i = 0; i < 2; i++)
        af[i] = ld_frag(&Al[(wy + 16 * i + l15) * 136 + 32 * ks + quad * 8]);
#pragma unroll
      for (int j = 0; j < 2; j++)
        bfr[j] = ld_frag(&Bl[(wx + 16 * j + l15) * 136 + 32 * ks + quad * 8]);
#pragma unroll
      for (int i = 0; i < 2; i++)
#pragma unroll
        for (int j = 0; j < 2; j++)
          acc[i][j] = __builtin_amdgcn_mfma_f32_16x16x32_bf16(af[i], bfr[j], acc[i][j], 0, 0, 0);
    }
  }
#pragma unroll
  for (int i = 0; i < 2; i++)
#pragma unroll
    for (int j = 0; j < 2; j++) {
      int col = c0 + wx + 16 * j + l15;
      float bv = bias[col];
#pragma unroll
      for (int r = 0; r < 4; r++) {
        int row = i0 + wy + 16 * i + quad * 4 + r;
        out[(size_t)row * 128 + col] = acc[i][j][r] + bv;
      }
    }
}

extern "C" void kernel_launch(void* const* d_in, const int* in_sizes, int n_in,
                              void* d_out, int out_size, void* d_ws, size_t ws_size,
                              hipStream_t stream) {
  const float* x      = (const float*)d_in[0];
  const float* ln_w   = (const float*)d_in[1];
  const float* ln_b   = (const float*)d_in[2];
  const float* w_qkv  = (const float*)d_in[3];
  const float* scale  = (const float*)d_in[4];
  const float* w_proj = (const float*)d_in[5];
  const float* b_proj = (const float*)d_in[6];
  float* out = (float*)d_out;

  char* ws = (char*)d_ws;
  unsigned short* xn     = (unsigned short*)(ws);               // 4 MB
  unsigned short* wqkvT  = (unsigned short*)(ws + 4194304);     // 768 KB
  unsigned short* wprojT = (unsigned short*)(ws + 4980736);     // 256 KB
  unsigned short* qk     = (unsigned short*)(ws + 5242880);     // 64 MB [16384][2048] bf16
  unsigned short* Vt     = (unsigned short*)(ws + 72351744);    // 32 MB [128][128][1024] fp16
  unsigned short* aout   = (unsigned short*)(ws + 105906176);   // 32 MB bf16
  // total ws use: ~139 MB

  ln_kernel<<<dim3(4096), dim3(256), 0, stream>>>(x, ln_w, ln_b, xn);
  tcast_kernel<<<dim3(96, 4), dim3(256), 0, stream>>>(w_qkv, wqkvT, 128, 3072);
  tcast_kernel<<<dim3(4, 32), dim3(256), 0, stream>>>(w_proj, wprojT, 1024, 128);
  qkv_gemm<<<dim3(128, 24), dim3(256), 0, stream>>>(xn, wqkvT, scale, qk, Vt);
  attn_kernel<<<dim3(1024), dim3(256), 0, stream>>>(qk, Vt, aout);
  proj_gemm<<<dim3(256, 2), dim3(256), 0, stream>>>(aout, wprojT, b_proj, out);
}

// Round 10
// 184.678 us; speedup vs baseline: 1.0668x; 1.0668x over previous
//
#include <hip/hip_runtime.h>
#include <hip/hip_bf16.h>

// Problem dims: B=16, N=1024, E=d_head=128, H=8; M = 16384 rows
typedef __bf16 bf16x8 __attribute__((ext_vector_type(8)));
typedef _Float16 f16x8 __attribute__((ext_vector_type(8)));
typedef float f32x4 __attribute__((ext_vector_type(4)));

__device__ __forceinline__ unsigned short f2bf(float f) {
  union { __hip_bfloat16 h; unsigned short u; } cv;
  cv.h = __float2bfloat16(f);
  return cv.u;
}
__device__ __forceinline__ unsigned short f2h(float f) {
  union { _Float16 h; unsigned short u; } cv;
  cv.h = (_Float16)f;
  return cv.u;
}
// pack 2 f32 -> 2 f16 in one dword (v_cvt_pkrtz_f16_f32); a -> bits[15:0]
__device__ __forceinline__ unsigned int pkrtz(float a, float b) {
  auto h = __builtin_amdgcn_cvt_pkrtz(a, b);  // __fp16 ext_vector(2)
  unsigned int u;
  __builtin_memcpy(&u, &h, 4);
  return u;
}

__device__ __forceinline__ bf16x8 ld_frag(const unsigned short* p) {
  bf16x8 v;
  __builtin_memcpy(&v, __builtin_assume_aligned(p, 16), 16);
  return v;
}
__device__ __forceinline__ f16x8 ld_f16x8(const unsigned short* p) {
  f16x8 v;
  __builtin_memcpy(&v, __builtin_assume_aligned(p, 16), 16);
  return v;
}
__device__ __forceinline__ uint4 ld16(const unsigned short* p) {
  uint4 v;
  __builtin_memcpy(&v, __builtin_assume_aligned(p, 16), 16);
  return v;
}
__device__ __forceinline__ void st16(unsigned short* p, uint4 v) {
  __builtin_memcpy(__builtin_assume_aligned(p, 16), &v, 16);
}
// async global->LDS DMA, 16 B per lane; lds dest is wave-uniform base + lane*16
__device__ __forceinline__ void dma16(const unsigned short* g, unsigned short* l) {
  __builtin_amdgcn_global_load_lds((const __attribute__((address_space(1))) void*)g,
                                   (__attribute__((address_space(3))) void*)l, 16, 0, 0);
}

// ---------------- LayerNorm + cast to bf16 -----------------
__global__ __launch_bounds__(256) void ln_kernel(const float* __restrict__ x,
                                                 const float* __restrict__ w,
                                                 const float* __restrict__ b,
                                                 unsigned short* __restrict__ xn) {
  int wave = threadIdx.x >> 6;
  int lane = threadIdx.x & 63;
  int row = blockIdx.x * 4 + wave;
  const float* xr = x + (size_t)row * 128;
  float2 v = *reinterpret_cast<const float2*>(xr + lane * 2);
  float s1 = v.x + v.y;
  float s2 = v.x * v.x + v.y * v.y;
#pragma unroll
  for (int off = 32; off > 0; off >>= 1) {
    s1 += __shfl_xor(s1, off, 64);
    s2 += __shfl_xor(s2, off, 64);
  }
  float mu = s1 * (1.0f / 128.0f);
  float var = s2 * (1.0f / 128.0f) - mu * mu;
  float rstd = rsqrtf(var + 1e-5f);
  float a0 = (v.x - mu) * rstd * w[lane * 2] + b[lane * 2];
  float a1 = (v.y - mu) * rstd * w[lane * 2 + 1] + b[lane * 2 + 1];
  unsigned int pk = (unsigned int)f2bf(a0) | ((unsigned int)f2bf(a1) << 16);
  *reinterpret_cast<unsigned int*>(xn + (size_t)row * 128 + lane * 2) = pk;
}

// ---------------- transpose + cast fp32[R][C] -> bf16[C][R] -----------------
__global__ __launch_bounds__(256) void tcast_kernel(const float* __restrict__ in,
                                                    unsigned short* __restrict__ out,
                                                    int R, int C) {
  __shared__ float tile[32][33];
  int tx = threadIdx.x & 31, ty = threadIdx.x >> 5;
  int c0 = blockIdx.x * 32, r0 = blockIdx.y * 32;
#pragma unroll
  for (int k = 0; k < 4; k++)
    tile[ty + 8 * k][tx] = in[(size_t)(r0 + ty + 8 * k) * C + c0 + tx];
  __syncthreads();
#pragma unroll
  for (int k = 0; k < 4; k++)
    out[(size_t)(c0 + ty + 8 * k) * R + r0 + tx] = f2bf(tile[tx][ty + 8 * k]);
}

// ---------------- QKV GEMM, 128x128 tile, BK=64 x2 ----------------
// Q cols (0..1023, pre-scaled by scale[h]) and K cols -> qk bf16;
// V cols -> Vt[bh][d][n'] fp16, where n' is the PV-slot token permutation:
// t = 32c+16s+4q+r  ->  n' = 32c+8q+4s+r. This makes each attn lane's 8
// P-values (tokens {16s+4*quad+r} from the QK^T C-layout) CONTIGUOUS in Vt,
// so the K=32 PV needs no cross-lane P redistribution (MFMA is k-order-
// invariant when A and B share the ordering).
__global__ __launch_bounds__(256) void qkv_gemm(const unsigned short* __restrict__ A,
                                                const unsigned short* __restrict__ Bt,
                                                const float* __restrict__ scale,
                                                unsigned short* __restrict__ qk,
                                                unsigned short* __restrict__ Vt) {
  __shared__ unsigned short Al[128 * 72];
  __shared__ unsigned short Bl[128 * 72];
  int t = threadIdx.x;
  int i0 = blockIdx.x * 128, c0 = blockIdx.y * 128;
  int lg = t & 7, rr = t >> 3;  // granule 0..7, row 0..31
  int w = t >> 6, lane = t & 63, l15 = lane & 15, quad = lane >> 4;
  int wy = (w >> 1) * 64, wx = (w & 1) * 64;
  const f32x4 fz = {0.f, 0.f, 0.f, 0.f};
  f32x4 acc[4][4];
#pragma unroll
  for (int i = 0; i < 4; i++)
#pragma unroll
    for (int j = 0; j < 4; j++) acc[i][j] = fz;

#pragma unroll
  for (int kt = 0; kt < 2; kt++) {
    int k0 = kt * 64;
    uint4 areg[4], breg[4];
#pragma unroll
    for (int p = 0; p < 4; p++)
      areg[p] = ld16(&A[(size_t)(i0 + rr + 32 * p) * 128 + k0 + lg * 8]);
#pragma unroll
    for (int p = 0; p < 4; p++)
      breg[p] = ld16(&Bt[(size_t)(c0 + rr + 32 * p) * 128 + k0 + lg * 8]);
    __syncthreads();
#pragma unroll
    for (int p = 0; p < 4; p++) st16(&Al[(rr + 32 * p) * 72 + lg * 8], areg[p]);
#pragma unroll
    for (int p = 0; p < 4; p++) st16(&Bl[(rr + 32 * p) * 72 + lg * 8], breg[p]);
    __syncthreads();
#pragma unroll
    for (int ks = 0; ks < 2; ks++) {
      bf16x8 af[4], bfr[4];
#pragma unroll
      for (int i = 0; i < 4; i++)
        af[i] = ld_frag(&Al[(wy + 16 * i + l15) * 72 + 32 * ks + quad * 8]);
#pragma unroll
      for (int j = 0; j < 4; j++)
        bfr[j] = ld_frag(&Bl[(wx + 16 * j + l15) * 72 + 32 * ks + quad * 8]);
#pragma unroll
      for (int i = 0; i < 4; i++)
#pragma unroll
        for (int j = 0; j < 4; j++)
          acc[i][j] = __builtin_amdgcn_mfma_f32_16x16x32_bf16(af[i], bfr[j], acc[i][j], 0, 0, 0);
    }
  }
  if (blockIdx.y < 16) {
    // Q blocks (y<8) carry scale[h] folded in; h == blockIdx.y for y<8
    float qsc = (blockIdx.y < 8) ? scale[blockIdx.y] : 1.0f;
#pragma unroll
    for (int i = 0; i < 4; i++)
#pragma unroll
      for (int j = 0; j < 4; j++)
#pragma unroll
        for (int r = 0; r < 4; r++) {
          int row = i0 + wy + 16 * i + quad * 4 + r;
          int col = c0 + wx + 16 * j + l15;
          qk[(size_t)row * 2048 + col] = f2bf(acc[i][j][r] * qsc);
        }
  } else {
    int vc0 = (blockIdx.y - 16) * 128;
#pragma unroll
    for (int i = 0; i < 4; i++)
#pragma unroll
      for (int j = 0; j < 4; j++) {
        int vcol = vc0 + wx + 16 * j + l15;   // 0..1023
        int hh = vcol >> 7, dd = vcol & 127;
        int row0 = i0 + wy + 16 * i + quad * 4;
        int bb = row0 >> 10, nn = row0 & 1023;
        // PV-slot permutation within each 32-token block (nn%4==0 -> the
        // ushort4 stays contiguous: only bits [4:2] of nn are remapped)
        int nnp = (nn & ~31) | (((nn >> 2) & 3) << 3) | (((nn >> 4) & 1) << 2) | (nn & 3);
        ushort4 pk;
        pk.x = f2h(acc[i][j][0]); pk.y = f2h(acc[i][j][1]);
        pk.z = f2h(acc[i][j][2]); pk.w = f2h(acc[i][j][3]);
        *reinterpret_cast<ushort4*>(Vt + (size_t)(bb * 8 + hh) * 131072 +
                                    (size_t)dd * 1024 + nnp) = pk;
      }
  }
}

// ---------------- Flash attention: 1 barrier/kt, K=32 PV, MFMA row-sum -----
// block = (b,h, 128-row Q tile); 4 waves x 32 rows (2 groups of 16).
// Structure (R8-proven): K+V double-buffered, 64 KB LDS, ONE __syncthreads
// per kt (drains DMAs issued a full iteration ago), prefetch K/V[kt+1] after
// it. PV at full-rate K=32 f16 with zero-shuffle P (Vt token-permuted).
// SINGLE change vs R8: denominator via ones-column MFMA — osum[g] += P x ones
// computes the row-sum on the matrix pipe in C-layout (row=quad*4+r), deleting
// 32 v_add/lane-kt AND the epilogue shuffle redistribution. Softmax stays
// __expf (R9 post-mortem: __builtin_exp2f lowers to PRECISE ocml exp2 with
// range fix-up, +10us VALU — native __expf's v_mul+v_exp is cheaper).
__global__ __launch_bounds__(256, 2) void attn_kernel(const unsigned short* __restrict__ qk,
                                                      const unsigned short* __restrict__ Vt,
                                                      unsigned short* __restrict__ aout) {
  __shared__ __align__(16) unsigned short Kl[2][64 * 128];  // 32 KB [kcol][d], granule-swizzled
  __shared__ __align__(16) unsigned short Vl[2][128 * 64];  // 32 KB [d][tok'], granule-swizzled
  int t = threadIdx.x;
  int idx = blockIdx.x;
  // same-bh q-tiles at blockIdx stride 128 (=0 mod 8) -> same XCD slot
  int bh = idx & 127, qt = idx >> 7;
  int b = bh >> 3, h = bh & 7;
  int q0 = qt * 128;
  int w = t >> 6, lane = t & 63, l15 = lane & 15, quad = lane >> 4;

  // Q fragments (B-operand layout: n=l15=qrow, k=quad*8+j), 2 groups of 16
  bf16x8 qf[2][4];
  {
    const unsigned short* qb = qk + (size_t)(b * 1024) * 2048 + h * 128;
#pragma unroll
    for (int g = 0; g < 2; g++) {
      const unsigned short* qp = qb + (size_t)(q0 + 32 * w + 16 * g + l15) * 2048;
#pragma unroll
      for (int ks = 0; ks < 4; ks++) qf[g][ks] = ld_frag(qp + 32 * ks + quad * 8);
    }
  }
  const f32x4 fz = {0.f, 0.f, 0.f, 0.f};
  f32x4 o[2][8];
#pragma unroll
  for (int g = 0; g < 2; g++)
#pragma unroll
    for (int i = 0; i < 8; i++) o[g][i] = fz;
  f32x4 osum[2] = {fz, fz};  // row-sum accumulator (C-layout: row=quad*4+r)
  const f16x8 vones = {1.f16, 1.f16, 1.f16, 1.f16, 1.f16, 1.f16, 1.f16, 1.f16};

  const unsigned short* kbase = qk + (size_t)(b * 1024) * 2048 + 1024 + h * 128;
  const unsigned short* vbase = Vt + (size_t)bh * 131072;

  // DMA lane mappings (4 K-chunks + 4 V-chunks per wave, 1 KB each)
  int koff[4], voff[4];
#pragma unroll
  for (int i = 0; i < 4; i++) {
    int c = w * 4 + i;
    int krow = c * 4 + (lane >> 4);                    // 0..63 (kcol)
    int kg = ((lane & 15) ^ (krow & 7)) * 8;           // 16B granule * 8 shorts
    koff[i] = krow * 2048 + kg;
    int vrow = c * 8 + (lane >> 3);                    // 0..127 (d)
    int vg = ((lane & 7) ^ ((vrow >> 1) & 7)) * 8;
    voff[i] = vrow * 1024 + vg;
  }

  // prologue: preload K[0] and V[0] into buffer 0
#pragma unroll
  for (int i = 0; i < 4; i++) {
    dma16(kbase + koff[i], &Kl[0][(w * 4 + i) * 512]);
    dma16(vbase + voff[i], &Vl[0][(w * 4 + i) * 512]);
  }

  for (int kt = 0; kt < 16; kt++) {
    int k0 = kt * 64;
    __syncthreads();  // drains K[kt]+V[kt] (issued a full iteration ago);
                      // all waves done reading buf[(kt+1)&1] one iter ago
    if (kt < 15) {
      int kn0 = (kt + 1) * 64;
      int nb = (kt + 1) & 1;
#pragma unroll
      for (int i = 0; i < 4; i++) {
        dma16(kbase + (size_t)kn0 * 2048 + koff[i], &Kl[nb][(w * 4 + i) * 512]);
        dma16(vbase + voff[i] + kn0, &Vl[nb][(w * 4 + i) * 512]);
      }
    }
    const unsigned short* Kc = Kl[kt & 1];
    const unsigned short* Vc = Vl[kt & 1];

    // ---- QK^T + exp + pack to K=32 A-frags (own lane's tokens only) ----
    f16x8 pa[2][2];  // [g][cp]; slots j=4s+r -> token 32cp+16s+4*quad+r
#pragma unroll
    for (int cp = 0; cp < 2; cp++) {
      unsigned int dw[2][4];
#pragma unroll
      for (int sub = 0; sub < 2; sub++) {
        int ct = cp * 2 + sub;
        f32x4 acc[2] = {fz, fz};
#pragma unroll
        for (int ks = 0; ks < 4; ks++) {
          bf16x8 kf = ld_frag(&Kc[(16 * ct + l15) * 128 + ((4 * ks + quad) ^ (l15 & 7)) * 8]);
#pragma unroll
          for (int g = 0; g < 2; g++)
            acc[g] = __builtin_amdgcn_mfma_f32_16x16x32_bf16(kf, qf[g][ks], acc[g], 0, 0, 0);
        }
#pragma unroll
        for (int g = 0; g < 2; g++) {
          float p[4];
          if ((q0 + 32 * w + 16 * g) == (k0 + 16 * ct)) {
#pragma unroll
            for (int r = 0; r < 4; r++)
              p[r] = ((quad * 4 + r) == l15) ? 0.f : __expf(acc[g][r]);
          } else {
#pragma unroll
            for (int r = 0; r < 4; r++) p[r] = __expf(acc[g][r]);
          }
          dw[g][sub * 2 + 0] = pkrtz(p[0], p[1]);
          dw[g][sub * 2 + 1] = pkrtz(p[2], p[3]);
        }
      }
#pragma unroll
      for (int g = 0; g < 2; g++) __builtin_memcpy(&pa[g][cp], dw[g], 16);
    }

    // ---- O += P * V at K=32; row-sum += P * ones (denominator on MFMA) ----
    // (V[kt] was drained by THIS iteration's top barrier; no mid barrier)
#pragma unroll
    for (int cp = 0; cp < 2; cp++) {
#pragma unroll
      for (int g = 0; g < 2; g++)
        osum[g] = __builtin_amdgcn_mfma_f32_16x16x32_f16(pa[g][cp], vones, osum[g], 0, 0, 0);
#pragma unroll
      for (int c8 = 0; c8 < 8; c8++) {
        // row d=16c8+l15; 16B granule (4cp+quad) swizzled by (d>>1)&7=(l15>>1)&7
        f16x8 vf = ld_f16x8(&Vc[(16 * c8 + l15) * 64 + ((4 * cp + quad) ^ ((l15 >> 1) & 7)) * 8]);
#pragma unroll
        for (int g = 0; g < 2; g++)
          o[g][c8] = __builtin_amdgcn_mfma_f32_16x16x32_f16(pa[g][cp], vf, o[g][c8], 0, 0, 0);
      }
    }
  }

  // epilogue: osum[g][r] = softmax denominator for qrow=quad*4+r (16g group),
  // already in the same C-layout as o — direct divide, no shuffles.
#pragma unroll
  for (int g = 0; g < 2; g++) {
#pragma unroll
    for (int r = 0; r < 4; r++) {
      float rl = 1.0f / osum[g][r];
      int row = b * 1024 + q0 + 32 * w + 16 * g + quad * 4 + r;
#pragma unroll
      for (int c8 = 0; c8 < 8; c8++) {
        int col = h * 128 + 16 * c8 + l15;
        aout[(size_t)row * 1024 + col] = f2bf(o[g][c8][r] * rl);
      }
    }
  }
}

// ---------------- output projection: out = aout @ w_proj + b_proj (fp32) ----
// 64-row x 64-col blocks (512 total -> 2/CU), BK=128 x 8
__global__ __launch_bounds__(256) void proj_gemm(const unsigned short* __restrict__ A,
                                                 const unsigned short* __restrict__ Bt,
                                                 const float* __restrict__ bias,
                                                 float* __restrict__ out) {
  __shared__ unsigned short Al[64 * 136];
  __shared__ unsigned short Bl[64 * 136];
  int t = threadIdx.x;
  int i0 = blockIdx.x * 64, c0 = blockIdx.y * 64;
  int w = t >> 6, lane = t & 63, l15 = lane & 15, quad = lane >> 4;
  int wy = (w >> 1) * 32, wx = (w & 1) * 32;
  const f32x4 fz = {0.f, 0.f, 0.f, 0.f};
  f32x4 acc[2][2];
#pragma unroll
  for (int i = 0; i < 2; i++)
#pragma unroll
    for (int j = 0; j < 2; j++) acc[i][j] = fz;
  int l = t & 15, rr = t >> 4;
  for (int kb = 0; kb < 8; kb++) {
    int k0 = kb * 128;
    uint4 areg[4], breg[4];
#pragma unroll
    for (int p = 0; p < 4; p++)
      areg[p] = ld16(&A[(size_t)(i0 + rr + 16 * p) * 1024 + k0 + l * 8]);
#pragma unroll
    for (int p = 0; p < 4; p++)
      breg[p] = ld16(&Bt[(size_t)(c0 + rr + 16 * p) * 1024 + k0 + l * 8]);
    __syncthreads();
#pragma unroll
    for (int p = 0; p < 4; p++) st16(&Al[(rr + 16 * p) * 136 + l * 8], areg[p]);
#pragma unroll
    for (int p = 0; p < 4; p++) st16(&Bl[(rr + 16 * p) * 136 + l * 8], breg[p]);
    __syncthreads();
#pragma unroll
    for (int ks = 0; ks < 4; ks++) {
      bf16x8 af[2], bfr[2];
#pragma unroll
      for (int i = 0; i < 2; i++)
        af[i] = ld_frag(&Al[(wy + 16 * i + l15) * 136 + 32 * ks + quad * 8]);
#pragma unroll
      for (int j = 0; j < 2; j++)
        bfr[j] = ld_frag(&Bl[(wx + 16 * j + l15) * 136 + 32 * ks + quad * 8]);
#pragma unroll
      for (int i = 0; i < 2; i++)
#pragma unroll
        for (int j = 0; j < 2; j++)
          acc[i][j] = __builtin_amdgcn_mfma_f32_16x16x32_bf16(af[i], bfr[j], acc[i][j], 0, 0, 0);
    }
  }
#pragma unroll
  for (int i = 0; i < 2; i++)
#pragma unroll
    for (int j = 0; j < 2; j++) {
      int col = c0 + wx + 16 * j + l15;
      float bv = bias[col];
#pragma unroll
      for (int r = 0; r < 4; r++) {
        int row = i0 + wy + 16 * i + quad * 4 + r;
        out[(size_t)row * 128 + col] = acc[i][j][r] + bv;
      }
    }
}

extern "C" void kernel_launch(void* const* d_in, const int* in_sizes, int n_in,
                              void* d_out, int out_size, void* d_ws, size_t ws_size,
                              hipStream_t stream) {
  const float* x      = (const float*)d_in[0];
  const float* ln_w   = (const float*)d_in[1];
  const float* ln_b   = (const float*)d_in[2];
  const float* w_qkv  = (const float*)d_in[3];
  const float* scale  = (const float*)d_in[4];
  const float* w_proj = (const float*)d_in[5];
  const float* b_proj = (const float*)d_in[6];
  float* out = (float*)d_out;

  char* ws = (char*)d_ws;
  unsigned short* xn     = (unsigned short*)(ws);               // 4 MB
  unsigned short* wqkvT  = (unsigned short*)(ws + 4194304);     // 768 KB
  unsigned short* wprojT = (unsigned short*)(ws + 4980736);     // 256 KB
  unsigned short* qk     = (unsigned short*)(ws + 5242880);     // 64 MB [16384][2048] bf16
  unsigned short* Vt     = (unsigned short*)(ws + 72351744);    // 32 MB [128][128][1024] fp16
  unsigned short* aout   = (unsigned short*)(ws + 105906176);   // 32 MB bf16
  // total ws use: ~139 MB

  ln_kernel<<<dim3(4096), dim3(256), 0, stream>>>(x, ln_w, ln_b, xn);
  tcast_kernel<<<dim3(96, 4), dim3(256), 0, stream>>>(w_qkv, wqkvT, 128, 3072);
  tcast_kernel<<<dim3(4, 32), dim3(256), 0, stream>>>(w_proj, wprojT, 1024, 128);
  qkv_gemm<<<dim3(128, 24), dim3(256), 0, stream>>>(xn, wqkvT, scale, qk, Vt);
  attn_kernel<<<dim3(1024), dim3(256), 0, stream>>>(qk, Vt, aout);
  proj_gemm<<<dim3(256, 2), dim3(256), 0, stream>>>(aout, wprojT, b_proj, out);
}